// Round 3
// baseline (32.507 us; speedup 1.0000x reference)
//
#include <hip/hip_runtime.h>

#define KAPPA 0.276f
#define NTRI 8256        // 128*129/2
#define BATCH 1024
#define SCALE (1.0f / (128.0f * 1024.0f))   // /trace2(=128) and /B mean

__global__ __launch_bounds__(256) void trace_kernel(const float* __restrict__ net_out,
                                                    const float* __restrict__ U1,
                                                    float* __restrict__ out) {
    const int b   = blockIdx.x;
    const int tid = threadIdx.x;
    const int w   = tid >> 6;     // wave 0..3: handles rows i = w, w+4, ..., w+124
    const int l   = tid & 63;     // lane: owns row elements k = 2l, 2l+1

    // coeffs: site of k=2l (and 2l+1) is exactly l -> coalesced per-lane loads
    const float cA = -2.0f * KAPPA * cosf(U1[(size_t)b * 128 + l]);
    const float cB = -2.0f * KAPPA * cosf(U1[(size_t)b * 128 + 64 + l]);

    // partner lanes (slot-preserving): kA=(k+16)&127, kB=(k&0x70)|((k+2)&15)
    const int lA = (l + 8) & 63;
    const int lB = (l & 0x38) | ((l + 1) & 7);

    const float* __restrict__ base = net_out + (size_t)b * NTRI;

    float sq = 0.f, hA = 0.f, hB = 0.f;
    int i   = w;
    int tri = (w * (w + 1)) >> 1;     // tri(i) = i(i+1)/2

    #pragma unroll 8
    for (int t = 0; t < 32; ++t) {
        // row i: lane reads k=2l,2l+1; reads past row-end stay in-bounds
        // (they land in the next rows; max addr = tri(127)+127 = 8255)
        float v0 = base[tri + 2 * l];
        float v1 = base[tri + 2 * l + 1];
        float x0 = (2 * l     <= i) ? v0 : 0.f;   // zero beyond diagonal:
        float x1 = (2 * l + 1 <= i) ? v1 : 0.f;   // kills invalid pair products too
        sq += x0 * x0 + x1 * x1;
        float xA0 = __shfl(x0, lA, 64);
        float xA1 = __shfl(x1, lA, 64);
        float xB0 = __shfl(x0, lB, 64);
        float xB1 = __shfl(x1, lB, 64);
        hA += x0 * xA0 + x1 * xA1;
        hB += x0 * xB0 + x1 * xB1;
        tri += (i << 2) + 10;         // tri(i+4) - tri(i) = 4i + 10
        i   += 4;
    }

    float val = sq + cA * hA + cB * hB;

    // wave reduce
    #pragma unroll
    for (int off = 32; off > 0; off >>= 1)
        val += __shfl_down(val, off, 64);

    __shared__ float red[4];
    if (l == 0) red[w] = val;
    __syncthreads();
    if (tid == 0)
        atomicAdd(out, (red[0] + red[1] + red[2] + red[3]) * SCALE);
}

extern "C" void kernel_launch(void* const* d_in, const int* in_sizes, int n_in,
                              void* d_out, int out_size, void* d_ws, size_t ws_size,
                              hipStream_t stream) {
    const float* net_out = (const float*)d_in[0];  // (1024, 8256) fp32
    const float* U1      = (const float*)d_in[1];  // (1024, 2, 8, 8) fp32
    float* out = (float*)d_out;                    // scalar fp32

    hipMemsetAsync(out, 0, sizeof(float), stream);
    trace_kernel<<<BATCH, 256, 0, stream>>>(net_out, U1, out);
}